// Round 13
// baseline (92.062 us; speedup 1.0000x reference)
//
#include <hip/hip_runtime.h>

// Problem constants: B=16, L=1024, K=8, N=64, Hh=64
#define NBL 16384

// workspace float offsets
#define WS_HPOW 0            // [NBL][8]
#define WS_YSUM 131072       // [NBL]
#define WS_AVG  147456       // [B][K]
#define WS_FRAG 147584       // u32[16896] pre-split weight fragment table
#define WS_CODE 164480       // u32[NBL] packed j-codes (separate: k_mlp idempotent)

// output float offsets
#define OFF_V  0
#define OFF_H  262144
#define OFF_Y  17039360
#define OFF_BT 19136512
#define OFF_BY 19267584
#define OFF_BH 19398656
#define OFF_BD 19529728

typedef short s8v __attribute__((ext_vector_type(8)));
typedef float f32x16 __attribute__((ext_vector_type(16)));
typedef float f32x4 __attribute__((ext_vector_type(4)));
typedef unsigned int u32x4 __attribute__((ext_vector_type(4)));

#define MFMA(a, b, c) __builtin_amdgcn_mfma_f32_32x32x16_bf16(a, b, c, 0, 0, 0)
#define NCALL 22   // 2 (L1) + 8 (L2) + 8 (L3) + 4 (heads)

// ---------------------------------------------------------------- helpers
__device__ __forceinline__ unsigned packbf(float x, float y) {
  return (__float_as_uint(x) >> 16) | (__float_as_uint(y) & 0xFFFF0000u);
}

// exact 3-term truncation split of fp32 (4th term is identically zero)
__device__ __forceinline__ void split3(float x, float& a, float& b, float& c) {
  a = __uint_as_float(__float_as_uint(x) & 0xFFFF0000u);
  const float r1 = x - a;
  b = __uint_as_float(__float_as_uint(r1) & 0xFFFF0000u);
  c = r1 - b;
}

__device__ __forceinline__ void build_frags3(const float* v, s8v* F) {
  float s0[8], s1[8], s2[8];
  #pragma unroll
  for (int e = 0; e < 8; e++) split3(v[e], s0[e], s1[e], s2[e]);
  u32x4 w0, w1, w2;
  w0.x = packbf(s0[0], s0[1]); w0.y = packbf(s0[2], s0[3]);
  w0.z = packbf(s0[4], s0[5]); w0.w = packbf(s0[6], s0[7]);
  w1.x = packbf(s1[0], s1[1]); w1.y = packbf(s1[2], s1[3]);
  w1.z = packbf(s1[4], s1[5]); w1.w = packbf(s1[6], s1[7]);
  w2.x = packbf(s2[0], s2[1]); w2.y = packbf(s2[2], s2[3]);
  w2.z = packbf(s2[4], s2[5]); w2.w = packbf(s2[6], s2[7]);
  F[0] = __builtin_bit_cast(s8v, w0);
  F[1] = __builtin_bit_cast(s8v, w1);
  F[2] = __builtin_bit_cast(s8v, w2);
}

// 8-product emulated-fp32 MAC (bit-identical to R4 mac10, zero terms removed)
__device__ __forceinline__ f32x16 mac8(const s8v* A, const s8v* B, f32x16 c) {
  c = MFMA(A[0], B[0], c);
  c = MFMA(A[0], B[1], c); c = MFMA(A[1], B[0], c);
  c = MFMA(A[0], B[2], c); c = MFMA(A[1], B[1], c); c = MFMA(A[2], B[0], c);
  c = MFMA(A[1], B[2], c); c = MFMA(A[2], B[1], c);
  return c;
}

__device__ __forceinline__ void frag_ld(const u32x4* __restrict__ sFr, int call,
                                        int lane, s8v* F) {
  F[0] = __builtin_bit_cast(s8v, sFr[(call * 3 + 0) * 64 + lane]);
  F[1] = __builtin_bit_cast(s8v, sFr[(call * 3 + 1) * 64 + lane]);
  F[2] = __builtin_bit_cast(s8v, sFr[(call * 3 + 2) * 64 + lane]);
}

// weight element for staging: A[j=32M+(lane&31)][ic=16T+8*(lane>>5)+e]
__device__ __forceinline__ float w_elem(int call, int lane, int e,
                                        const float* __restrict__ W1,
                                        const float* __restrict__ W2,
                                        const float* __restrict__ W3,
                                        const float* __restrict__ Wy,
                                        const float* __restrict__ Wh,
                                        const float* __restrict__ Wd) {
  const int h = lane >> 5, m = lane & 31;
  if (call < 2) {
    const int ic = 8 * h + e;
    return (ic < 9) ? W1[ic * 64 + call * 32 + m] : 0.0f;
  } else if (call < 10) {
    const int idx = call - 2, T = idx >> 1, M = idx & 1;
    return W2[(16 * T + 8 * h + e) * 64 + 32 * M + m];
  } else if (call < 18) {
    const int idx = call - 10, T = idx >> 1, M = idx & 1;
    return W3[(16 * T + 8 * h + e) * 64 + 32 * M + m];
  } else {
    const int ic = 16 * (call - 18) + 8 * h + e;
    if (m < 5)  return Wy[ic * 5 + m];
    if (m < 10) return Wh[ic * 5 + m - 5];
    if (m < 15) return Wd[ic * 5 + m - 10];
    return 0.0f;
  }
}

__device__ __forceinline__ f32x16 cinit(const float* bias, int M, int half) {
  f32x16 c;
  #pragma unroll
  for (int o = 0; o < 4; o++) {
    const float4 b4 = *(const float4*)(bias + M * 32 + o * 8 + 4 * half);
    c[4 * o + 0] = b4.x; c[4 * o + 1] = b4.y;
    c[4 * o + 2] = b4.z; c[4 * o + 3] = b4.w;
  }
  return c;
}

__device__ __forceinline__ f32x16 relu16(f32x16 a) {
  #pragma unroll
  for (int i = 0; i < 16; i++) a[i] = fmaxf(a[i], 0.0f);
  return a;
}

// B-fragment for kstep T from previous layer's C registers (R10 known-good)
template <int T>
__device__ __forceinline__ void bfragC3(const f32x16& P0, const f32x16& P1,
                                        int half, s8v* F) {
  float v[8];
  #pragma unroll
  for (int m = 0; m < 4; m++) {
    float lo, hi;
    if ((T >> 1) == 0) { lo = P0[8 * (T & 1) + m]; hi = P0[8 * (T & 1) + 4 + m]; }
    else               { lo = P1[8 * (T & 1) + m]; hi = P1[8 * (T & 1) + 4 + m]; }
    const float own  = half ? hi : lo;
    const float send = half ? lo : hi;
    const float recv = __shfl_xor(send, 32, 64);
    v[m]     = half ? recv : own;
    v[4 + m] = half ? own : recv;
  }
  build_frags3(v, F);
}

// compile-time gscale: same IEEE double ops as runtime version, folded
template <int E>   // fsize = 2^E
__device__ __forceinline__ float gscl(int j) {
  constexpr double fs = (double)(1 << E);
  switch (j) {
    case 1:  return (float)(1.0 / sqrt(fs * 7.0));
    case 2:  return (float)(1.0 / sqrt(fs * 127.0));
    case 3:  return (float)(1.0 / sqrt(fs * 2047.0));
    default: return (float)(1.0 / sqrt(fs * 32767.0));
  }
}

template <int E>
__device__ __forceinline__ void qparamsE(int j, const float* __restrict__ sv,
                                         float& se, float& qn, float& qp) {
  se = 1.0f; qn = 0.0f; qp = 0.0f;
  if (j > 0) {
    const int p = 1 << (4 * j - 1);            // 8,128,2048,32768
    const float gs = gscl<E>(j);
    const float s  = sv[j - 1];
    const float sg = s * gs;
    se = sg + (s - sg);                        // literal forward of s_eff
    qn = -(float)p; qp = (float)(p - 1);
  }
}

__device__ __forceinline__ float quantv(float x, float seff, float qn, float qp) {
  float xs = fminf(fmaxf(x / seff, qn), qp);   // exact IEEE div (decision path)
  float r  = rintf(xs);                        // round half-even == jnp.round
  return (xs + (r - xs)) * seff;
}

// reciprocal-multiply variant for bulk streaming
__device__ __forceinline__ float quantr(float x, float rcp, float seff,
                                        float qn, float qp) {
  float xs = fminf(fmaxf(x * rcp, qn), qp);
  float r  = rintf(xs);
  return (xs + (r - xs)) * seff;
}

// ---------------------------------------------------------------- kernel A
// blocks < NBL: per-(b,l) power sums; blocks >= NBL: pre-split frag table
__global__ __launch_bounds__(256) void k_power(const float* __restrict__ Hm,
                                               const float* __restrict__ ym,
                                               const float* __restrict__ W1,
                                               const float* __restrict__ W2,
                                               const float* __restrict__ W3,
                                               const float* __restrict__ Wy,
                                               const float* __restrict__ Wh,
                                               const float* __restrict__ Wd,
                                               float* __restrict__ ws) {
  const int t = threadIdx.x;
  if (blockIdx.x >= NBL) {   // frag-table prep (66 blocks x 256 = 16896)
    const int i = (blockIdx.x - NBL) * 256 + t;
    const int call = i / 768;
    const int rem  = i - call * 768;
    const int sp   = rem >> 8;
    const int ln   = (rem >> 2) & 63;
    const int wd   = rem & 3;
    const float x0 = w_elem(call, ln, 2 * wd,     W1, W2, W3, Wy, Wh, Wd);
    const float x1 = w_elem(call, ln, 2 * wd + 1, W1, W2, W3, Wy, Wh, Wd);
    float a0, b0, c0, a1, b1, c1;
    split3(x0, a0, b0, c0);
    split3(x1, a1, b1, c1);
    const float lo = (sp == 0) ? a0 : (sp == 1) ? b0 : c0;
    const float hi = (sp == 0) ? a1 : (sp == 1) ? b1 : c1;
    ((unsigned*)ws)[WS_FRAG + i] = packbf(lo, hi);
    return;
  }
  const int bl = blockIdx.x;
  __shared__ float wsum[4][8];
  float4 h4 = *(const float4*)(Hm + bl * 1024 + t * 4);
  float s0 = h4.x * h4.x + h4.y * h4.y;
  float s1 = h4.z * h4.z + h4.w * h4.w;
  #pragma unroll
  for (int m = 4; m <= 32; m <<= 1) {
    s0 += __shfl_xor(s0, m, 64);
    s1 += __shfl_xor(s1, m, 64);
  }
  const int lane = t & 63, w = t >> 6;
  if (lane < 4) {
    wsum[w][2 * lane]     = s0;
    wsum[w][2 * lane + 1] = s1;
  }
  __syncthreads();
  if (t < 8)
    ws[WS_HPOW + bl * 8 + t] = wsum[0][t] + wsum[1][t] + wsum[2][t] + wsum[3][t];
  if (t >= 64 && t < 128) {
    const int u = t - 64;
    float p = 0.0f;
    if (u < 32) {
      float4 v4 = *(const float4*)(ym + bl * 128 + u * 4);
      p = v4.x * v4.x + v4.y * v4.y + v4.z * v4.z + v4.w * v4.w;
    }
    #pragma unroll
    for (int m = 1; m <= 32; m <<= 1) p += __shfl_xor(p, m, 64);
    if (u == 0) ws[WS_YSUM + bl] = p;
  }
}

// ---------------------------------------------------------------- kernel B
__global__ __launch_bounds__(256) void k_avg(float* __restrict__ ws) {
  const int bk = blockIdx.x;
  const int b = bk >> 3, k = bk & 7;
  const int t = threadIdx.x;
  __shared__ float red[256];
  float p = 0.0f;
  for (int l = t; l < 1024; l += 256)
    p += ws[WS_HPOW + ((b << 10) + l) * 8 + k];
  red[t] = p;
  __syncthreads();
  for (int st = 128; st > 0; st >>= 1) {
    if (t < st) red[t] += red[t + st];
    __syncthreads();
  }
  if (t == 0) ws[WS_AVG + bk] = red[0] * (1.0f / 1024.0f);
}

// ---------------------------------------------------------------- kernel C
// wave = 32 sites (4 bl); MLP + decisions + b-links + v_q; codes -> WS_CODE.
// IDEMPOTENT (reads HPOW/YSUM/AVG/FRAG, writes only CODE + out slices) so it
// can be launched twice for exact duration measurement via the total delta.
__global__ __launch_bounds__(512, 3) void k_mlp(
    const float* __restrict__ v,  const float* __restrict__ snr,
    const float* __restrict__ gy, const float* __restrict__ gH,
    const float* __restrict__ gd,
    const float* __restrict__ B1, const float* __restrict__ B2,
    const float* __restrict__ B3,
    const float* __restrict__ By, const float* __restrict__ Bh,
    const float* __restrict__ Bd,
    const float* __restrict__ sd,
    float* __restrict__ ws, float* __restrict__ out) {

  __shared__ u32x4 sFr[NCALL * 192];             // 67584 B pre-split A-frags
  __shared__ float sB1v[64], sB2v[64], sB3v[64], sBHv[32];

  const int t = threadIdx.x;
  {
    const u32x4* gsrc = (const u32x4*)((const unsigned*)ws + WS_FRAG);
    for (int i = t; i < NCALL * 192; i += 512) sFr[i] = gsrc[i];
  }
  if (t < 64) { sB1v[t] = B1[t]; sB2v[t] = B2[t]; sB3v[t] = B3[t]; }
  if (t < 32) sBHv[t] = (t < 5) ? By[t] : (t < 10) ? Bh[t - 5]
                       : (t < 15) ? Bd[t - 10] : 0.0f;
  __syncthreads();

  const int w    = t >> 6;
  const int lane = t & 63;
  const int half = lane >> 5;
  const int site = lane & 31;
  const int bl0  = (blockIdx.x * 8 + w) * 4;   // 4 bl per wave
  const int bl   = bl0 + (site >> 3);
  const int k    = site & 7;

  // ---- features (registers only; half0: f0..f7, half1: f8 + zero pad)
  const float vr = v[bl * 16 + 2 * k], vi = v[bl * 16 + 2 * k + 1];
  s8v A0[3], A1[3], Bf[3];
  {
    float fv[8];
    if (half == 0) {
      float tot = 0.0f, hp = 0.0f;
      #pragma unroll
      for (int kk = 0; kk < 8; kk++) {
        const float hv = ws[WS_HPOW + bl * 8 + kk];
        tot += hv;
        if (kk == k) hp = hv;
      }
      fv[0] = vr;
      fv[1] = vi;
      fv[2] = snr[bl * 8 + k];
      fv[3] = hp;
      fv[4] = ws[WS_AVG + (bl >> 10) * 8 + k];
      fv[5] = log1pf(hp / (tot - hp + 1e-10f));
      fv[6] = log1pf(tot);
      fv[7] = log1pf(ws[WS_YSUM + bl]);
    } else {
      fv[0] = sqrtf(vr * vr + vi * vi + 1e-10f);
      #pragma unroll
      for (int e = 1; e < 8; e++) fv[e] = 0.0f;
    }
    build_frags3(fv, Bf);
  }

  // ---- layer 1 (K=16), with depth-1 A-frag prefetch
  frag_ld(sFr, 0, lane, A0);
  frag_ld(sFr, 1, lane, A1);
  f32x16 c0 = cinit(sB1v, 0, half), c1 = cinit(sB1v, 1, half);
  c0 = mac8(A0, Bf, c0); frag_ld(sFr, 2, lane, A0);
  c1 = mac8(A1, Bf, c1); frag_ld(sFr, 3, lane, A1);
  c0 = relu16(c0); c1 = relu16(c1);

  // ---- layer 2 (K=64, 4 ksteps); A-frags for kstep T+1 load under kstep T
  {
    f32x16 n0 = cinit(sB2v, 0, half), n1 = cinit(sB2v, 1, half);
    bfragC3<0>(c0, c1, half, Bf);
    n0 = mac8(A0, Bf, n0); frag_ld(sFr, 4, lane, A0);
    n1 = mac8(A1, Bf, n1); frag_ld(sFr, 5, lane, A1);
    bfragC3<1>(c0, c1, half, Bf);
    n0 = mac8(A0, Bf, n0); frag_ld(sFr, 6, lane, A0);
    n1 = mac8(A1, Bf, n1); frag_ld(sFr, 7, lane, A1);
    bfragC3<2>(c0, c1, half, Bf);
    n0 = mac8(A0, Bf, n0); frag_ld(sFr, 8, lane, A0);
    n1 = mac8(A1, Bf, n1); frag_ld(sFr, 9, lane, A1);
    bfragC3<3>(c0, c1, half, Bf);
    n0 = mac8(A0, Bf, n0); frag_ld(sFr, 10, lane, A0);
    n1 = mac8(A1, Bf, n1); frag_ld(sFr, 11, lane, A1);
    c0 = relu16(n0); c1 = relu16(n1);
  }
  // ---- layer 3 (calls 10..17; 18,19 prefetched at tail for heads)
  {
    f32x16 n0 = cinit(sB3v, 0, half), n1 = cinit(sB3v, 1, half);
    bfragC3<0>(c0, c1, half, Bf);
    n0 = mac8(A0, Bf, n0); frag_ld(sFr, 12, lane, A0);
    n1 = mac8(A1, Bf, n1); frag_ld(sFr, 13, lane, A1);
    bfragC3<1>(c0, c1, half, Bf);
    n0 = mac8(A0, Bf, n0); frag_ld(sFr, 14, lane, A0);
    n1 = mac8(A1, Bf, n1); frag_ld(sFr, 15, lane, A1);
    bfragC3<2>(c0, c1, half, Bf);
    n0 = mac8(A0, Bf, n0); frag_ld(sFr, 16, lane, A0);
    n1 = mac8(A1, Bf, n1); frag_ld(sFr, 17, lane, A1);
    bfragC3<3>(c0, c1, half, Bf);
    n0 = mac8(A0, Bf, n0); frag_ld(sFr, 18, lane, A0);
    n1 = mac8(A1, Bf, n1); frag_ld(sFr, 19, lane, A1);
    c0 = relu16(n0); c1 = relu16(n1);
  }
  // ---- heads (M-tile 0 only; rows 15..31 zero); calls 18..21, A0/A1 alt
  f32x16 hc = cinit(sBHv, 0, half);
  {
    bfragC3<0>(c0, c1, half, Bf);
    hc = mac8(A0, Bf, hc); frag_ld(sFr, 20, lane, A0);
    bfragC3<1>(c0, c1, half, Bf);
    hc = mac8(A1, Bf, hc); frag_ld(sFr, 21, lane, A1);
    bfragC3<2>(c0, c1, half, Bf);
    hc = mac8(A0, Bf, hc);
    bfragC3<3>(c0, c1, half, Bf);
    hc = mac8(A1, Bf, hc);
  }

  // ---- gather all 16 logits of this lane's site into registers (R10 path)
  float ho[16];
  {
    float hop[8];
    #pragma unroll
    for (int r = 0; r < 8; r++) hop[r] = __shfl_xor(hc[r], 32, 64);
    if (half == 0) {
      #pragma unroll
      for (int r = 0; r < 8; r++) {
        ho[8 * (r >> 2) + (r & 3)]     = hc[r];
        ho[8 * (r >> 2) + 4 + (r & 3)] = hop[r];
      }
    } else {
      #pragma unroll
      for (int r = 0; r < 8; r++) {
        ho[8 * (r >> 2) + 4 + (r & 3)] = hc[r];
        ho[8 * (r >> 2) + (r & 3)]     = hop[r];
      }
    }
  }

  // ---- decisions (all lanes redundant; exact R5 math)
  int bjH, bjD, bjY;
  {
    const float* gg = gH + (bl0 * 8 + site) * 5;
    float bv = ho[5] + gg[0]; int bj = 0;
    #pragma unroll
    for (int c = 1; c < 5; c++) {
      const float lv = ho[5 + c] + gg[c];
      if (lv > bv) { bv = lv; bj = c; }
    }
    bjH = bj;
  }
  {
    const float* gg = gd + (bl0 * 8 + site) * 5;
    float bv = ho[10] + gg[0]; int bj = 0;
    #pragma unroll
    for (int c = 1; c < 5; c++) {
      const float lv = ho[10 + c] + gg[c];
      if (lv > bv) { bv = lv; bj = c; }
    }
    bjD = bj;
  }
  {
    const int gb = lane & 24;
    const float* gg = gy + bl * 5;
    float bv = 0.0f; int bj = 0;
    #pragma unroll
    for (int c = 0; c < 5; c++) {
      float acc = 0.0f;
      #pragma unroll
      for (int kk = 0; kk < 8; kk++) acc += __shfl(ho[c], gb + kk, 64);
      const float lv = acc * 0.125f + gg[c];
      if (c == 0 || lv > bv) { bv = lv; bj = c; }
    }
    bjY = bj;
  }

  // ---- pack H j-codes (3b x 8) + y j-code (3b at bit 27) per bl
  unsigned cH = 0;
  #pragma unroll
  for (int kk = 0; kk < 8; kk++)
    cH |= ((unsigned)__shfl(bjH, (lane & 24) + kk, 64)) << (3 * kk);
  cH |= ((unsigned)bjY) << 27;

  if (lane < 32) {
    if ((site & 7) == 0)
      ((unsigned*)ws)[WS_CODE + bl] = cH;       // fresh area: idempotent
    {   // b-links
      const int oi = bl0 * 8 + site;
      const float by_ = 64.0f  * (float)bjY;
      const float bH_ = 512.0f * (float)bjH;
      const float bd_ = 8.0f   * (float)bjD;
      out[OFF_BT + oi] = by_ + bH_ + bd_;
      out[OFF_BY + oi] = by_;
      out[OFF_BH + oi] = bH_;
      out[OFF_BD + oi] = bd_;
    }
    {   // v_q (exact-div path retained)
      float dse, dqn, dqp;
      qparamsE<18>(bjD, sd, dse, dqn, dqp);
      float2 r;
      r.x = quantv(vr, dse, dqn, dqp);
      r.y = quantv(vi, dse, dqn, dqp);
      *(float2*)(out + OFF_V + bl0 * 16 + site * 2) = r;
    }
  }
}

// ---------------------------------------------------------------- kernel D
// pure streaming quant: one wave per bl; reciprocal-mul + nontemporal stores
__global__ __launch_bounds__(256) void k_hq(const float* __restrict__ Hm,
                                            const float* __restrict__ ym,
                                            const float* __restrict__ sy,
                                            const float* __restrict__ sH,
                                            const float* __restrict__ ws,
                                            float* __restrict__ out) {
  const int t    = threadIdx.x;
  const int lane = t & 63;
  const int bl   = blockIdx.x * 4 + (t >> 6);

  const unsigned code = ((const unsigned*)ws)[WS_CODE + bl];
  const int k0 = (2 * lane) & 7;
  const int jA = (code >> (3 * k0)) & 7;
  const int jB = (code >> (3 * (k0 + 1))) & 7;
  const int jY = (code >> 27) & 7;

  float ase, aqn, aqp, bse, bqn, bqp, yse, yqn, yqp;
  qparamsE<24>(jA, sH, ase, aqn, aqp);
  qparamsE<24>(jB, sH, bse, bqn, bqp);
  qparamsE<21>(jY, sy, yse, yqn, yqp);
  const float arc = 1.0f / ase, brc = 1.0f / bse, yrc = 1.0f / yse;

  // ---- y_q: 32 float4 per bl
  if (lane < 32) {
    const int gi = bl * 128 + lane * 4;
    const float4 xv = *(const float4*)(ym + gi);
    f32x4 r;
    r.x = quantr(xv.x, yrc, yse, yqn, yqp);
    r.y = quantr(xv.y, yrc, yse, yqn, yqp);
    r.z = quantr(xv.z, yrc, yse, yqn, yqp);
    r.w = quantr(xv.w, yrc, yse, yqn, yqp);
    __builtin_nontemporal_store(r, (f32x4*)(out + OFF_Y + gi));
  }

  // ---- H_q: 256 float4 per bl, coalesced, nt stores (keep H in L3)
  const float* src = Hm + bl * 1024;
  float* dst = out + OFF_H + bl * 1024;
  #pragma unroll
  for (int c = 0; c < 4; c++) {
    const int fi = (c * 64 + lane) * 4;
    const float4 xh = *(const float4*)(src + fi);
    f32x4 r;
    r.x = quantr(xh.x, arc, ase, aqn, aqp);
    r.y = quantr(xh.y, arc, ase, aqn, aqp);
    r.z = quantr(xh.z, brc, bse, bqn, bqp);
    r.w = quantr(xh.w, brc, bse, bqn, bqp);
    __builtin_nontemporal_store(r, (f32x4*)(dst + fi));
  }
}

// ---------------------------------------------------------------- launch
extern "C" void kernel_launch(void* const* d_in, const int* in_sizes, int n_in,
                              void* d_out, int out_size, void* d_ws, size_t ws_size,
                              hipStream_t stream) {
  (void)in_sizes; (void)n_in; (void)out_size; (void)ws_size;
  const float* v   = (const float*)d_in[0];
  const float* Hm  = (const float*)d_in[1];
  const float* ym  = (const float*)d_in[2];
  const float* snr = (const float*)d_in[3];
  const float* gy  = (const float*)d_in[4];
  const float* gH  = (const float*)d_in[5];
  const float* gd  = (const float*)d_in[6];
  const float* W1  = (const float*)d_in[7];
  const float* B1  = (const float*)d_in[8];
  const float* W2  = (const float*)d_in[9];
  const float* B2  = (const float*)d_in[10];
  const float* W3  = (const float*)d_in[11];
  const float* B3  = (const float*)d_in[12];
  const float* Wy  = (const float*)d_in[13];
  const float* By  = (const float*)d_in[14];
  const float* Wh  = (const float*)d_in[15];
  const float* Bh  = (const float*)d_in[16];
  const float* Wd  = (const float*)d_in[17];
  const float* Bd  = (const float*)d_in[18];
  const float* sy  = (const float*)d_in[19];
  const float* sH  = (const float*)d_in[20];
  const float* sd  = (const float*)d_in[21];
  float* out = (float*)d_out;
  float* ws  = (float*)d_ws;

  k_power<<<NBL + 66, 256, 0, stream>>>(Hm, ym, W1, W2, W3, Wy, Wh, Wd, ws);
  k_avg<<<128, 256, 0, stream>>>(ws);
  // k_mlp launched TWICE (idempotent): total delta vs R12 == t(k_mlp)
  k_mlp<<<512, 512, 0, stream>>>(v, snr, gy, gH, gd,
                                 B1, B2, B3, By, Bh, Bd, sd, ws, out);
  k_mlp<<<512, 512, 0, stream>>>(v, snr, gy, gH, gd,
                                 B1, B2, B3, By, Bh, Bd, sd, ws, out);
  k_hq<<<4096, 256, 0, stream>>>(Hm, ym, sy, sH, ws, out);
}

// Round 15
// 71.066 us; speedup vs baseline: 1.2954x; 1.2954x over previous
//
#include <hip/hip_runtime.h>

// Problem constants: B=16, L=1024, K=8, N=64, Hh=64
#define NBL 16384

// workspace float offsets
#define WS_HPOW 0            // [NBL][8]
#define WS_YSUM 131072       // [NBL]
#define WS_AVG  147456       // [B][K]
#define WS_FRAG 147584       // u32[16896] pre-split weight fragment table
#define WS_CODE 164480       // u32[NBL] packed j-codes

// output float offsets
#define OFF_V  0
#define OFF_H  262144
#define OFF_Y  17039360
#define OFF_BT 19136512
#define OFF_BY 19267584
#define OFF_BH 19398656
#define OFF_BD 19529728

typedef short s8v __attribute__((ext_vector_type(8)));
typedef float f32x16 __attribute__((ext_vector_type(16)));
typedef float f32x4 __attribute__((ext_vector_type(4)));
typedef unsigned int u32x4 __attribute__((ext_vector_type(4)));

#define MFMA(a, b, c) __builtin_amdgcn_mfma_f32_32x32x16_bf16(a, b, c, 0, 0, 0)
#define NCALL 22   // 2 (L1) + 8 (L2) + 8 (L3) + 4 (heads)

// ---------------------------------------------------------------- helpers
__device__ __forceinline__ unsigned packbf(float x, float y) {
  return (__float_as_uint(x) >> 16) | (__float_as_uint(y) & 0xFFFF0000u);
}

// exact 3-term truncation split of fp32 (4th term is identically zero)
__device__ __forceinline__ void split3(float x, float& a, float& b, float& c) {
  a = __uint_as_float(__float_as_uint(x) & 0xFFFF0000u);
  const float r1 = x - a;
  b = __uint_as_float(__float_as_uint(r1) & 0xFFFF0000u);
  c = r1 - b;
}

__device__ __forceinline__ void build_frags3(const float* v, s8v* F) {
  float s0[8], s1[8], s2[8];
  #pragma unroll
  for (int e = 0; e < 8; e++) split3(v[e], s0[e], s1[e], s2[e]);
  u32x4 w0, w1, w2;
  w0.x = packbf(s0[0], s0[1]); w0.y = packbf(s0[2], s0[3]);
  w0.z = packbf(s0[4], s0[5]); w0.w = packbf(s0[6], s0[7]);
  w1.x = packbf(s1[0], s1[1]); w1.y = packbf(s1[2], s1[3]);
  w1.z = packbf(s1[4], s1[5]); w1.w = packbf(s1[6], s1[7]);
  w2.x = packbf(s2[0], s2[1]); w2.y = packbf(s2[2], s2[3]);
  w2.z = packbf(s2[4], s2[5]); w2.w = packbf(s2[6], s2[7]);
  F[0] = __builtin_bit_cast(s8v, w0);
  F[1] = __builtin_bit_cast(s8v, w1);
  F[2] = __builtin_bit_cast(s8v, w2);
}

// 8-product emulated-fp32 MAC (bit-identical to R4 mac10, zero terms removed)
__device__ __forceinline__ f32x16 mac8(const s8v* A, const s8v* B, f32x16 c) {
  c = MFMA(A[0], B[0], c);
  c = MFMA(A[0], B[1], c); c = MFMA(A[1], B[0], c);
  c = MFMA(A[0], B[2], c); c = MFMA(A[1], B[1], c); c = MFMA(A[2], B[0], c);
  c = MFMA(A[1], B[2], c); c = MFMA(A[2], B[1], c);
  return c;
}

__device__ __forceinline__ void frag_ld(const u32x4* __restrict__ sFr, int call,
                                        int lane, s8v* F) {
  F[0] = __builtin_bit_cast(s8v, sFr[(call * 3 + 0) * 64 + lane]);
  F[1] = __builtin_bit_cast(s8v, sFr[(call * 3 + 1) * 64 + lane]);
  F[2] = __builtin_bit_cast(s8v, sFr[(call * 3 + 2) * 64 + lane]);
}

// weight element for staging: A[j=32M+(lane&31)][ic=16T+8*(lane>>5)+e]
__device__ __forceinline__ float w_elem(int call, int lane, int e,
                                        const float* __restrict__ W1,
                                        const float* __restrict__ W2,
                                        const float* __restrict__ W3,
                                        const float* __restrict__ Wy,
                                        const float* __restrict__ Wh,
                                        const float* __restrict__ Wd) {
  const int h = lane >> 5, m = lane & 31;
  if (call < 2) {
    const int ic = 8 * h + e;
    return (ic < 9) ? W1[ic * 64 + call * 32 + m] : 0.0f;
  } else if (call < 10) {
    const int idx = call - 2, T = idx >> 1, M = idx & 1;
    return W2[(16 * T + 8 * h + e) * 64 + 32 * M + m];
  } else if (call < 18) {
    const int idx = call - 10, T = idx >> 1, M = idx & 1;
    return W3[(16 * T + 8 * h + e) * 64 + 32 * M + m];
  } else {
    const int ic = 16 * (call - 18) + 8 * h + e;
    if (m < 5)  return Wy[ic * 5 + m];
    if (m < 10) return Wh[ic * 5 + m - 5];
    if (m < 15) return Wd[ic * 5 + m - 10];
    return 0.0f;
  }
}

__device__ __forceinline__ f32x16 cinit(const float* bias, int M, int half) {
  f32x16 c;
  #pragma unroll
  for (int o = 0; o < 4; o++) {
    const float4 b4 = *(const float4*)(bias + M * 32 + o * 8 + 4 * half);
    c[4 * o + 0] = b4.x; c[4 * o + 1] = b4.y;
    c[4 * o + 2] = b4.z; c[4 * o + 3] = b4.w;
  }
  return c;
}

__device__ __forceinline__ f32x16 relu16(f32x16 a) {
  #pragma unroll
  for (int i = 0; i < 16; i++) a[i] = fmaxf(a[i], 0.0f);
  return a;
}

// B-fragment for kstep T from previous layer's C registers (R10 known-good)
template <int T>
__device__ __forceinline__ void bfragC3(const f32x16& P0, const f32x16& P1,
                                        int half, s8v* F) {
  float v[8];
  #pragma unroll
  for (int m = 0; m < 4; m++) {
    float lo, hi;
    if ((T >> 1) == 0) { lo = P0[8 * (T & 1) + m]; hi = P0[8 * (T & 1) + 4 + m]; }
    else               { lo = P1[8 * (T & 1) + m]; hi = P1[8 * (T & 1) + 4 + m]; }
    const float own  = half ? hi : lo;
    const float send = half ? lo : hi;
    const float recv = __shfl_xor(send, 32, 64);
    v[m]     = half ? recv : own;
    v[4 + m] = half ? own : recv;
  }
  build_frags3(v, F);
}

// compile-time gscale: same IEEE double ops as runtime version, folded
template <int E>   // fsize = 2^E
__device__ __forceinline__ float gscl(int j) {
  constexpr double fs = (double)(1 << E);
  switch (j) {
    case 1:  return (float)(1.0 / sqrt(fs * 7.0));
    case 2:  return (float)(1.0 / sqrt(fs * 127.0));
    case 3:  return (float)(1.0 / sqrt(fs * 2047.0));
    default: return (float)(1.0 / sqrt(fs * 32767.0));
  }
}

template <int E>
__device__ __forceinline__ void qparamsE(int j, const float* __restrict__ sv,
                                         float& se, float& qn, float& qp) {
  se = 1.0f; qn = 0.0f; qp = 0.0f;
  if (j > 0) {
    const int p = 1 << (4 * j - 1);            // 8,128,2048,32768
    const float gs = gscl<E>(j);
    const float s  = sv[j - 1];
    const float sg = s * gs;
    se = sg + (s - sg);                        // literal forward of s_eff
    qn = -(float)p; qp = (float)(p - 1);
  }
}

__device__ __forceinline__ float quantv(float x, float seff, float qn, float qp) {
  float xs = fminf(fmaxf(x / seff, qn), qp);   // exact IEEE div (decision path)
  float r  = rintf(xs);                        // round half-even == jnp.round
  return (xs + (r - xs)) * seff;
}

// reciprocal-multiply variant for bulk streaming
__device__ __forceinline__ float quantr(float x, float rcp, float seff,
                                        float qn, float qp) {
  float xs = fminf(fmaxf(x * rcp, qn), qp);
  float r  = rintf(xs);
  return (xs + (r - xs)) * seff;
}

// ---------------------------------------------------------------- kernel A
// blocks < NBL: per-(b,l) power sums; blocks >= NBL: pre-split frag table
__global__ __launch_bounds__(256) void k_power(const float* __restrict__ Hm,
                                               const float* __restrict__ ym,
                                               const float* __restrict__ W1,
                                               const float* __restrict__ W2,
                                               const float* __restrict__ W3,
                                               const float* __restrict__ Wy,
                                               const float* __restrict__ Wh,
                                               const float* __restrict__ Wd,
                                               float* __restrict__ ws) {
  const int t = threadIdx.x;
  if (blockIdx.x >= NBL) {   // frag-table prep (66 blocks x 256 = 16896)
    const int i = (blockIdx.x - NBL) * 256 + t;
    const int call = i / 768;
    const int rem  = i - call * 768;
    const int sp   = rem >> 8;
    const int ln   = (rem >> 2) & 63;
    const int wd   = rem & 3;
    const float x0 = w_elem(call, ln, 2 * wd,     W1, W2, W3, Wy, Wh, Wd);
    const float x1 = w_elem(call, ln, 2 * wd + 1, W1, W2, W3, Wy, Wh, Wd);
    float a0, b0, c0, a1, b1, c1;
    split3(x0, a0, b0, c0);
    split3(x1, a1, b1, c1);
    const float lo = (sp == 0) ? a0 : (sp == 1) ? b0 : c0;
    const float hi = (sp == 0) ? a1 : (sp == 1) ? b1 : c1;
    ((unsigned*)ws)[WS_FRAG + i] = packbf(lo, hi);
    return;
  }
  const int bl = blockIdx.x;
  __shared__ float wsum[4][8];
  float4 h4 = *(const float4*)(Hm + bl * 1024 + t * 4);
  float s0 = h4.x * h4.x + h4.y * h4.y;
  float s1 = h4.z * h4.z + h4.w * h4.w;
  #pragma unroll
  for (int m = 4; m <= 32; m <<= 1) {
    s0 += __shfl_xor(s0, m, 64);
    s1 += __shfl_xor(s1, m, 64);
  }
  const int lane = t & 63, w = t >> 6;
  if (lane < 4) {
    wsum[w][2 * lane]     = s0;
    wsum[w][2 * lane + 1] = s1;
  }
  __syncthreads();
  if (t < 8)
    ws[WS_HPOW + bl * 8 + t] = wsum[0][t] + wsum[1][t] + wsum[2][t] + wsum[3][t];
  if (t >= 64 && t < 128) {
    const int u = t - 64;
    float p = 0.0f;
    if (u < 32) {
      float4 v4 = *(const float4*)(ym + bl * 128 + u * 4);
      p = v4.x * v4.x + v4.y * v4.y + v4.z * v4.z + v4.w * v4.w;
    }
    #pragma unroll
    for (int m = 1; m <= 32; m <<= 1) p += __shfl_xor(p, m, 64);
    if (u == 0) ws[WS_YSUM + bl] = p;
  }
}

// ---------------------------------------------------------------- kernel B
__global__ __launch_bounds__(256) void k_avg(float* __restrict__ ws) {
  const int bk = blockIdx.x;
  const int b = bk >> 3, k = bk & 7;
  const int t = threadIdx.x;
  __shared__ float red[256];
  float p = 0.0f;
  for (int l = t; l < 1024; l += 256)
    p += ws[WS_HPOW + ((b << 10) + l) * 8 + k];
  red[t] = p;
  __syncthreads();
  for (int st = 128; st > 0; st >>= 1) {
    if (t < st) red[t] += red[t + st];
    __syncthreads();
  }
  if (t == 0) ws[WS_AVG + bk] = red[0] * (1.0f / 1024.0f);
}

// ---------------------------------------------------------------- kernel C
// wave = 32 sites (4 bl); MLP + decisions + b-links + v_q; codes -> WS_CODE
// (R12 known-good body, byte-for-byte)
__global__ __launch_bounds__(512, 3) void k_mlp(
    const float* __restrict__ v,  const float* __restrict__ snr,
    const float* __restrict__ gy, const float* __restrict__ gH,
    const float* __restrict__ gd,
    const float* __restrict__ B1, const float* __restrict__ B2,
    const float* __restrict__ B3,
    const float* __restrict__ By, const float* __restrict__ Bh,
    const float* __restrict__ Bd,
    const float* __restrict__ sd,
    float* __restrict__ ws, float* __restrict__ out) {

  __shared__ u32x4 sFr[NCALL * 192];             // 67584 B pre-split A-frags
  __shared__ float sB1v[64], sB2v[64], sB3v[64], sBHv[32];

  const int t = threadIdx.x;
  {
    const u32x4* gsrc = (const u32x4*)((const unsigned*)ws + WS_FRAG);
    for (int i = t; i < NCALL * 192; i += 512) sFr[i] = gsrc[i];
  }
  if (t < 64) { sB1v[t] = B1[t]; sB2v[t] = B2[t]; sB3v[t] = B3[t]; }
  if (t < 32) sBHv[t] = (t < 5) ? By[t] : (t < 10) ? Bh[t - 5]
                       : (t < 15) ? Bd[t - 10] : 0.0f;
  __syncthreads();

  const int w    = t >> 6;
  const int lane = t & 63;
  const int half = lane >> 5;
  const int site = lane & 31;
  const int bl0  = (blockIdx.x * 8 + w) * 4;   // 4 bl per wave
  const int bl   = bl0 + (site >> 3);
  const int k    = site & 7;

  // ---- features (registers only; half0: f0..f7, half1: f8 + zero pad)
  const float vr = v[bl * 16 + 2 * k], vi = v[bl * 16 + 2 * k + 1];
  s8v A0[3], A1[3], Bf[3];
  {
    float fv[8];
    if (half == 0) {
      float tot = 0.0f, hp = 0.0f;
      #pragma unroll
      for (int kk = 0; kk < 8; kk++) {
        const float hv = ws[WS_HPOW + bl * 8 + kk];
        tot += hv;
        if (kk == k) hp = hv;
      }
      fv[0] = vr;
      fv[1] = vi;
      fv[2] = snr[bl * 8 + k];
      fv[3] = hp;
      fv[4] = ws[WS_AVG + (bl >> 10) * 8 + k];
      fv[5] = log1pf(hp / (tot - hp + 1e-10f));
      fv[6] = log1pf(tot);
      fv[7] = log1pf(ws[WS_YSUM + bl]);
    } else {
      fv[0] = sqrtf(vr * vr + vi * vi + 1e-10f);
      #pragma unroll
      for (int e = 1; e < 8; e++) fv[e] = 0.0f;
    }
    build_frags3(fv, Bf);
  }

  // ---- layer 1 (K=16), with depth-1 A-frag prefetch
  frag_ld(sFr, 0, lane, A0);
  frag_ld(sFr, 1, lane, A1);
  f32x16 c0 = cinit(sB1v, 0, half), c1 = cinit(sB1v, 1, half);
  c0 = mac8(A0, Bf, c0); frag_ld(sFr, 2, lane, A0);
  c1 = mac8(A1, Bf, c1); frag_ld(sFr, 3, lane, A1);
  c0 = relu16(c0); c1 = relu16(c1);

  // ---- layer 2 (K=64, 4 ksteps); A-frags for kstep T+1 load under kstep T
  {
    f32x16 n0 = cinit(sB2v, 0, half), n1 = cinit(sB2v, 1, half);
    bfragC3<0>(c0, c1, half, Bf);
    n0 = mac8(A0, Bf, n0); frag_ld(sFr, 4, lane, A0);
    n1 = mac8(A1, Bf, n1); frag_ld(sFr, 5, lane, A1);
    bfragC3<1>(c0, c1, half, Bf);
    n0 = mac8(A0, Bf, n0); frag_ld(sFr, 6, lane, A0);
    n1 = mac8(A1, Bf, n1); frag_ld(sFr, 7, lane, A1);
    bfragC3<2>(c0, c1, half, Bf);
    n0 = mac8(A0, Bf, n0); frag_ld(sFr, 8, lane, A0);
    n1 = mac8(A1, Bf, n1); frag_ld(sFr, 9, lane, A1);
    bfragC3<3>(c0, c1, half, Bf);
    n0 = mac8(A0, Bf, n0); frag_ld(sFr, 10, lane, A0);
    n1 = mac8(A1, Bf, n1); frag_ld(sFr, 11, lane, A1);
    c0 = relu16(n0); c1 = relu16(n1);
  }
  // ---- layer 3 (calls 10..17; 18,19 prefetched at tail for heads)
  {
    f32x16 n0 = cinit(sB3v, 0, half), n1 = cinit(sB3v, 1, half);
    bfragC3<0>(c0, c1, half, Bf);
    n0 = mac8(A0, Bf, n0); frag_ld(sFr, 12, lane, A0);
    n1 = mac8(A1, Bf, n1); frag_ld(sFr, 13, lane, A1);
    bfragC3<1>(c0, c1, half, Bf);
    n0 = mac8(A0, Bf, n0); frag_ld(sFr, 14, lane, A0);
    n1 = mac8(A1, Bf, n1); frag_ld(sFr, 15, lane, A1);
    bfragC3<2>(c0, c1, half, Bf);
    n0 = mac8(A0, Bf, n0); frag_ld(sFr, 16, lane, A0);
    n1 = mac8(A1, Bf, n1); frag_ld(sFr, 17, lane, A1);
    bfragC3<3>(c0, c1, half, Bf);
    n0 = mac8(A0, Bf, n0); frag_ld(sFr, 18, lane, A0);
    n1 = mac8(A1, Bf, n1); frag_ld(sFr, 19, lane, A1);
    c0 = relu16(n0); c1 = relu16(n1);
  }
  // ---- heads (M-tile 0 only; rows 15..31 zero); calls 18..21, A0/A1 alt
  f32x16 hc = cinit(sBHv, 0, half);
  {
    bfragC3<0>(c0, c1, half, Bf);
    hc = mac8(A0, Bf, hc); frag_ld(sFr, 20, lane, A0);
    bfragC3<1>(c0, c1, half, Bf);
    hc = mac8(A1, Bf, hc); frag_ld(sFr, 21, lane, A1);
    bfragC3<2>(c0, c1, half, Bf);
    hc = mac8(A0, Bf, hc);
    bfragC3<3>(c0, c1, half, Bf);
    hc = mac8(A1, Bf, hc);
  }

  // ---- gather all 16 logits of this lane's site into registers (R10 path)
  float ho[16];
  {
    float hop[8];
    #pragma unroll
    for (int r = 0; r < 8; r++) hop[r] = __shfl_xor(hc[r], 32, 64);
    if (half == 0) {
      #pragma unroll
      for (int r = 0; r < 8; r++) {
        ho[8 * (r >> 2) + (r & 3)]     = hc[r];
        ho[8 * (r >> 2) + 4 + (r & 3)] = hop[r];
      }
    } else {
      #pragma unroll
      for (int r = 0; r < 8; r++) {
        ho[8 * (r >> 2) + 4 + (r & 3)] = hc[r];
        ho[8 * (r >> 2) + (r & 3)]     = hop[r];
      }
    }
  }

  // ---- decisions (all lanes redundant; exact R5 math)
  int bjH, bjD, bjY;
  {
    const float* gg = gH + (bl0 * 8 + site) * 5;
    float bv = ho[5] + gg[0]; int bj = 0;
    #pragma unroll
    for (int c = 1; c < 5; c++) {
      const float lv = ho[5 + c] + gg[c];
      if (lv > bv) { bv = lv; bj = c; }
    }
    bjH = bj;
  }
  {
    const float* gg = gd + (bl0 * 8 + site) * 5;
    float bv = ho[10] + gg[0]; int bj = 0;
    #pragma unroll
    for (int c = 1; c < 5; c++) {
      const float lv = ho[10 + c] + gg[c];
      if (lv > bv) { bv = lv; bj = c; }
    }
    bjD = bj;
  }
  {
    const int gb = lane & 24;
    const float* gg = gy + bl * 5;
    float bv = 0.0f; int bj = 0;
    #pragma unroll
    for (int c = 0; c < 5; c++) {
      float acc = 0.0f;
      #pragma unroll
      for (int kk = 0; kk < 8; kk++) acc += __shfl(ho[c], gb + kk, 64);
      const float lv = acc * 0.125f + gg[c];
      if (c == 0 || lv > bv) { bv = lv; bj = c; }
    }
    bjY = bj;
  }

  // ---- pack H j-codes (3b x 8) + y j-code (3b at bit 27) per bl
  unsigned cH = 0;
  #pragma unroll
  for (int kk = 0; kk < 8; kk++)
    cH |= ((unsigned)__shfl(bjH, (lane & 24) + kk, 64)) << (3 * kk);
  cH |= ((unsigned)bjY) << 27;

  if (lane < 32) {
    if ((site & 7) == 0)
      ((unsigned*)ws)[WS_CODE + bl] = cH;
    {   // b-links
      const int oi = bl0 * 8 + site;
      const float by_ = 64.0f  * (float)bjY;
      const float bH_ = 512.0f * (float)bjH;
      const float bd_ = 8.0f   * (float)bjD;
      out[OFF_BT + oi] = by_ + bH_ + bd_;
      out[OFF_BY + oi] = by_;
      out[OFF_BH + oi] = bH_;
      out[OFF_BD + oi] = bd_;
    }
    {   // v_q (exact-div path retained)
      float dse, dqn, dqp;
      qparamsE<18>(bjD, sd, dse, dqn, dqp);
      float2 r;
      r.x = quantv(vr, dse, dqn, dqp);
      r.y = quantv(vi, dse, dqn, dqp);
      *(float2*)(out + OFF_V + bl0 * 16 + site * 2) = r;
    }
  }
}

// ---------------------------------------------------------------- kernel D
// pure streaming quant: 2 bl per wave; reciprocal-mul + nontemporal stores
__global__ __launch_bounds__(256) void k_hq(const float* __restrict__ Hm,
                                            const float* __restrict__ ym,
                                            const float* __restrict__ sy,
                                            const float* __restrict__ sH,
                                            const float* __restrict__ ws,
                                            float* __restrict__ out) {
  const int t    = threadIdx.x;
  const int lane = t & 63;
  const int blb  = blockIdx.x * 8 + (t >> 6) * 2;

  #pragma unroll
  for (int bb = 0; bb < 2; bb++) {
    const int bl = blb + bb;
    const unsigned code = ((const unsigned*)ws)[WS_CODE + bl];
    const int k0 = (2 * lane) & 7;
    const int jA = (code >> (3 * k0)) & 7;
    const int jB = (code >> (3 * (k0 + 1))) & 7;
    const int jY = (code >> 27) & 7;

    float ase, aqn, aqp, bse, bqn, bqp, yse, yqn, yqp;
    qparamsE<24>(jA, sH, ase, aqn, aqp);
    qparamsE<24>(jB, sH, bse, bqn, bqp);
    qparamsE<21>(jY, sy, yse, yqn, yqp);
    const float arc = 1.0f / ase, brc = 1.0f / bse, yrc = 1.0f / yse;

    if (lane < 32) {   // y_q: 32 float4 per bl
      const int gi = bl * 128 + lane * 4;
      const float4 xv = *(const float4*)(ym + gi);
      f32x4 r;
      r.x = quantr(xv.x, yrc, yse, yqn, yqp);
      r.y = quantr(xv.y, yrc, yse, yqn, yqp);
      r.z = quantr(xv.z, yrc, yse, yqn, yqp);
      r.w = quantr(xv.w, yrc, yse, yqn, yqp);
      __builtin_nontemporal_store(r, (f32x4*)(out + OFF_Y + gi));
    }

    const float* src = Hm + bl * 1024;
    float* dst = out + OFF_H + bl * 1024;
    #pragma unroll
    for (int c = 0; c < 4; c++) {
      const int fi = (c * 64 + lane) * 4;
      const float4 xh = *(const float4*)(src + fi);
      f32x4 r;
      r.x = quantr(xh.x, arc, ase, aqn, aqp);
      r.y = quantr(xh.y, arc, ase, aqn, aqp);
      r.z = quantr(xh.z, brc, bse, bqn, bqp);
      r.w = quantr(xh.w, brc, bse, bqn, bqp);
      __builtin_nontemporal_store(r, (f32x4*)(dst + fi));
    }
  }
}

// ---------------------------------------------------------------- launch
extern "C" void kernel_launch(void* const* d_in, const int* in_sizes, int n_in,
                              void* d_out, int out_size, void* d_ws, size_t ws_size,
                              hipStream_t stream) {
  (void)in_sizes; (void)n_in; (void)out_size; (void)ws_size;
  const float* v   = (const float*)d_in[0];
  const float* Hm  = (const float*)d_in[1];
  const float* ym  = (const float*)d_in[2];
  const float* snr = (const float*)d_in[3];
  const float* gy  = (const float*)d_in[4];
  const float* gH  = (const float*)d_in[5];
  const float* gd  = (const float*)d_in[6];
  const float* W1  = (const float*)d_in[7];
  const float* B1  = (const float*)d_in[8];
  const float* W2  = (const float*)d_in[9];
  const float* B2  = (const float*)d_in[10];
  const float* W3  = (const float*)d_in[11];
  const float* B3  = (const float*)d_in[12];
  const float* Wy  = (const float*)d_in[13];
  const float* By  = (const float*)d_in[14];
  const float* Wh  = (const float*)d_in[15];
  const float* Bh  = (const float*)d_in[16];
  const float* Wd  = (const float*)d_in[17];
  const float* Bd  = (const float*)d_in[18];
  const float* sy  = (const float*)d_in[19];
  const float* sH  = (const float*)d_in[20];
  const float* sd  = (const float*)d_in[21];
  float* out = (float*)d_out;
  float* ws  = (float*)d_ws;

  k_power<<<NBL + 66, 256, 0, stream>>>(Hm, ym, W1, W2, W3, Wy, Wh, Wd, ws);
  k_avg<<<128, 256, 0, stream>>>(ws);
  k_mlp<<<512, 512, 0, stream>>>(v, snr, gy, gH, gd,
                                 B1, B2, B3, By, Bh, Bd, sd, ws, out);
  k_hq<<<2048, 256, 0, stream>>>(Hm, ym, sy, sH, ws, out);
}

// Round 16
// 69.227 us; speedup vs baseline: 1.3298x; 1.0266x over previous
//
#include <hip/hip_runtime.h>

// Problem constants: B=16, L=1024, K=8, N=64, Hh=64
#define NBL 16384

// workspace float offsets
#define WS_HPOW 0            // [NBL][8]
#define WS_YSUM 131072       // [NBL]
#define WS_AVG  147456       // [B][K]
#define WS_FRAG 147584       // u32[16896] pre-split weight fragment table
#define WS_CODE 164480       // u32[NBL] packed j-codes

// output float offsets
#define OFF_V  0
#define OFF_H  262144
#define OFF_Y  17039360
#define OFF_BT 19136512
#define OFF_BY 19267584
#define OFF_BH 19398656
#define OFF_BD 19529728

typedef short s8v __attribute__((ext_vector_type(8)));
typedef float f32x16 __attribute__((ext_vector_type(16)));
typedef float f32x4 __attribute__((ext_vector_type(4)));
typedef unsigned int u32x4 __attribute__((ext_vector_type(4)));

#define MFMA(a, b, c) __builtin_amdgcn_mfma_f32_32x32x16_bf16(a, b, c, 0, 0, 0)
#define NCALL 22   // 2 (L1) + 8 (L2) + 8 (L3) + 4 (heads)

// ---------------------------------------------------------------- helpers
__device__ __forceinline__ unsigned packbf(float x, float y) {
  return (__float_as_uint(x) >> 16) | (__float_as_uint(y) & 0xFFFF0000u);
}

// exact 3-term truncation split of fp32 (4th term is identically zero)
__device__ __forceinline__ void split3(float x, float& a, float& b, float& c) {
  a = __uint_as_float(__float_as_uint(x) & 0xFFFF0000u);
  const float r1 = x - a;
  b = __uint_as_float(__float_as_uint(r1) & 0xFFFF0000u);
  c = r1 - b;
}

__device__ __forceinline__ void build_frags3(const float* v, s8v* F) {
  float s0[8], s1[8], s2[8];
  #pragma unroll
  for (int e = 0; e < 8; e++) split3(v[e], s0[e], s1[e], s2[e]);
  u32x4 w0, w1, w2;
  w0.x = packbf(s0[0], s0[1]); w0.y = packbf(s0[2], s0[3]);
  w0.z = packbf(s0[4], s0[5]); w0.w = packbf(s0[6], s0[7]);
  w1.x = packbf(s1[0], s1[1]); w1.y = packbf(s1[2], s1[3]);
  w1.z = packbf(s1[4], s1[5]); w1.w = packbf(s1[6], s1[7]);
  w2.x = packbf(s2[0], s2[1]); w2.y = packbf(s2[2], s2[3]);
  w2.z = packbf(s2[4], s2[5]); w2.w = packbf(s2[6], s2[7]);
  F[0] = __builtin_bit_cast(s8v, w0);
  F[1] = __builtin_bit_cast(s8v, w1);
  F[2] = __builtin_bit_cast(s8v, w2);
}

// 8-product emulated-fp32 MAC (bit-identical to R4 mac10, zero terms removed)
__device__ __forceinline__ f32x16 mac8(const s8v* A, const s8v* B, f32x16 c) {
  c = MFMA(A[0], B[0], c);
  c = MFMA(A[0], B[1], c); c = MFMA(A[1], B[0], c);
  c = MFMA(A[0], B[2], c); c = MFMA(A[1], B[1], c); c = MFMA(A[2], B[0], c);
  c = MFMA(A[1], B[2], c); c = MFMA(A[2], B[1], c);
  return c;
}

__device__ __forceinline__ void frag_ld(const u32x4* __restrict__ sFr, int call,
                                        int lane, s8v* F) {
  F[0] = __builtin_bit_cast(s8v, sFr[(call * 3 + 0) * 64 + lane]);
  F[1] = __builtin_bit_cast(s8v, sFr[(call * 3 + 1) * 64 + lane]);
  F[2] = __builtin_bit_cast(s8v, sFr[(call * 3 + 2) * 64 + lane]);
}

// weight element for staging: A[j=32M+(lane&31)][ic=16T+8*(lane>>5)+e]
__device__ __forceinline__ float w_elem(int call, int lane, int e,
                                        const float* __restrict__ W1,
                                        const float* __restrict__ W2,
                                        const float* __restrict__ W3,
                                        const float* __restrict__ Wy,
                                        const float* __restrict__ Wh,
                                        const float* __restrict__ Wd) {
  const int h = lane >> 5, m = lane & 31;
  if (call < 2) {
    const int ic = 8 * h + e;
    return (ic < 9) ? W1[ic * 64 + call * 32 + m] : 0.0f;
  } else if (call < 10) {
    const int idx = call - 2, T = idx >> 1, M = idx & 1;
    return W2[(16 * T + 8 * h + e) * 64 + 32 * M + m];
  } else if (call < 18) {
    const int idx = call - 10, T = idx >> 1, M = idx & 1;
    return W3[(16 * T + 8 * h + e) * 64 + 32 * M + m];
  } else {
    const int ic = 16 * (call - 18) + 8 * h + e;
    if (m < 5)  return Wy[ic * 5 + m];
    if (m < 10) return Wh[ic * 5 + m - 5];
    if (m < 15) return Wd[ic * 5 + m - 10];
    return 0.0f;
  }
}

__device__ __forceinline__ f32x16 cinit(const float* bias, int M, int half) {
  f32x16 c;
  #pragma unroll
  for (int o = 0; o < 4; o++) {
    const float4 b4 = *(const float4*)(bias + M * 32 + o * 8 + 4 * half);
    c[4 * o + 0] = b4.x; c[4 * o + 1] = b4.y;
    c[4 * o + 2] = b4.z; c[4 * o + 3] = b4.w;
  }
  return c;
}

__device__ __forceinline__ f32x16 relu16(f32x16 a) {
  #pragma unroll
  for (int i = 0; i < 16; i++) a[i] = fmaxf(a[i], 0.0f);
  return a;
}

// B-fragment for kstep T from previous layer's C registers (R10 known-good)
template <int T>
__device__ __forceinline__ void bfragC3(const f32x16& P0, const f32x16& P1,
                                        int half, s8v* F) {
  float v[8];
  #pragma unroll
  for (int m = 0; m < 4; m++) {
    float lo, hi;
    if ((T >> 1) == 0) { lo = P0[8 * (T & 1) + m]; hi = P0[8 * (T & 1) + 4 + m]; }
    else               { lo = P1[8 * (T & 1) + m]; hi = P1[8 * (T & 1) + 4 + m]; }
    const float own  = half ? hi : lo;
    const float send = half ? lo : hi;
    const float recv = __shfl_xor(send, 32, 64);
    v[m]     = half ? recv : own;
    v[4 + m] = half ? own : recv;
  }
  build_frags3(v, F);
}

// compile-time gscale: same IEEE double ops as runtime version, folded
template <int E>   // fsize = 2^E
__device__ __forceinline__ float gscl(int j) {
  constexpr double fs = (double)(1 << E);
  switch (j) {
    case 1:  return (float)(1.0 / sqrt(fs * 7.0));
    case 2:  return (float)(1.0 / sqrt(fs * 127.0));
    case 3:  return (float)(1.0 / sqrt(fs * 2047.0));
    default: return (float)(1.0 / sqrt(fs * 32767.0));
  }
}

template <int E>
__device__ __forceinline__ void qparamsE(int j, const float* __restrict__ sv,
                                         float& se, float& qn, float& qp) {
  se = 1.0f; qn = 0.0f; qp = 0.0f;
  if (j > 0) {
    const int p = 1 << (4 * j - 1);            // 8,128,2048,32768
    const float gs = gscl<E>(j);
    const float s  = sv[j - 1];
    const float sg = s * gs;
    se = sg + (s - sg);                        // literal forward of s_eff
    qn = -(float)p; qp = (float)(p - 1);
  }
}

__device__ __forceinline__ float quantv(float x, float seff, float qn, float qp) {
  float xs = fminf(fmaxf(x / seff, qn), qp);   // exact IEEE div (decision path)
  float r  = rintf(xs);                        // round half-even == jnp.round
  return (xs + (r - xs)) * seff;
}

// reciprocal-multiply variant for bulk streaming
__device__ __forceinline__ float quantr(float x, float rcp, float seff,
                                        float qn, float qp) {
  float xs = fminf(fmaxf(x * rcp, qn), qp);
  float r  = rintf(xs);
  return (xs + (r - xs)) * seff;
}

// ---------------------------------------------------------------- kernel A
// blocks < NBL: per-(b,l) power sums; blocks >= NBL: pre-split frag table
__global__ __launch_bounds__(256) void k_power(const float* __restrict__ Hm,
                                               const float* __restrict__ ym,
                                               const float* __restrict__ W1,
                                               const float* __restrict__ W2,
                                               const float* __restrict__ W3,
                                               const float* __restrict__ Wy,
                                               const float* __restrict__ Wh,
                                               const float* __restrict__ Wd,
                                               float* __restrict__ ws) {
  const int t = threadIdx.x;
  if (blockIdx.x >= NBL) {   // frag-table prep (66 blocks x 256 = 16896)
    const int i = (blockIdx.x - NBL) * 256 + t;
    const int call = i / 768;
    const int rem  = i - call * 768;
    const int sp   = rem >> 8;
    const int ln   = (rem >> 2) & 63;
    const int wd   = rem & 3;
    const float x0 = w_elem(call, ln, 2 * wd,     W1, W2, W3, Wy, Wh, Wd);
    const float x1 = w_elem(call, ln, 2 * wd + 1, W1, W2, W3, Wy, Wh, Wd);
    float a0, b0, c0, a1, b1, c1;
    split3(x0, a0, b0, c0);
    split3(x1, a1, b1, c1);
    const float lo = (sp == 0) ? a0 : (sp == 1) ? b0 : c0;
    const float hi = (sp == 0) ? a1 : (sp == 1) ? b1 : c1;
    ((unsigned*)ws)[WS_FRAG + i] = packbf(lo, hi);
    return;
  }
  const int bl = blockIdx.x;
  __shared__ float wsum[4][8];
  float4 h4 = *(const float4*)(Hm + bl * 1024 + t * 4);
  float s0 = h4.x * h4.x + h4.y * h4.y;
  float s1 = h4.z * h4.z + h4.w * h4.w;
  #pragma unroll
  for (int m = 4; m <= 32; m <<= 1) {
    s0 += __shfl_xor(s0, m, 64);
    s1 += __shfl_xor(s1, m, 64);
  }
  const int lane = t & 63, w = t >> 6;
  if (lane < 4) {
    wsum[w][2 * lane]     = s0;
    wsum[w][2 * lane + 1] = s1;
  }
  __syncthreads();
  if (t < 8)
    ws[WS_HPOW + bl * 8 + t] = wsum[0][t] + wsum[1][t] + wsum[2][t] + wsum[3][t];
  if (t >= 64 && t < 128) {
    const int u = t - 64;
    float p = 0.0f;
    if (u < 32) {
      float4 v4 = *(const float4*)(ym + bl * 128 + u * 4);
      p = v4.x * v4.x + v4.y * v4.y + v4.z * v4.z + v4.w * v4.w;
    }
    #pragma unroll
    for (int m = 1; m <= 32; m <<= 1) p += __shfl_xor(p, m, 64);
    if (u == 0) ws[WS_YSUM + bl] = p;
  }
}

// ---------------------------------------------------------------- kernel B
__global__ __launch_bounds__(256) void k_avg(float* __restrict__ ws) {
  const int bk = blockIdx.x;
  const int b = bk >> 3, k = bk & 7;
  const int t = threadIdx.x;
  __shared__ float red[256];
  float p = 0.0f;
  for (int l = t; l < 1024; l += 256)
    p += ws[WS_HPOW + ((b << 10) + l) * 8 + k];
  red[t] = p;
  __syncthreads();
  for (int st = 128; st > 0; st >>= 1) {
    if (t < st) red[t] += red[t + st];
    __syncthreads();
  }
  if (t == 0) ws[WS_AVG + bk] = red[0] * (1.0f / 1024.0f);
}

// ---------------------------------------------------------------- kernel C
// wave = 32 sites (4 bl); MLP + decisions + b-links + v_q; codes -> WS_CODE
// (R12 known-good body, byte-for-byte)
__global__ __launch_bounds__(512, 3) void k_mlp(
    const float* __restrict__ v,  const float* __restrict__ snr,
    const float* __restrict__ gy, const float* __restrict__ gH,
    const float* __restrict__ gd,
    const float* __restrict__ B1, const float* __restrict__ B2,
    const float* __restrict__ B3,
    const float* __restrict__ By, const float* __restrict__ Bh,
    const float* __restrict__ Bd,
    const float* __restrict__ sd,
    float* __restrict__ ws, float* __restrict__ out) {

  __shared__ u32x4 sFr[NCALL * 192];             // 67584 B pre-split A-frags
  __shared__ float sB1v[64], sB2v[64], sB3v[64], sBHv[32];

  const int t = threadIdx.x;
  {
    const u32x4* gsrc = (const u32x4*)((const unsigned*)ws + WS_FRAG);
    for (int i = t; i < NCALL * 192; i += 512) sFr[i] = gsrc[i];
  }
  if (t < 64) { sB1v[t] = B1[t]; sB2v[t] = B2[t]; sB3v[t] = B3[t]; }
  if (t < 32) sBHv[t] = (t < 5) ? By[t] : (t < 10) ? Bh[t - 5]
                       : (t < 15) ? Bd[t - 10] : 0.0f;
  __syncthreads();

  const int w    = t >> 6;
  const int lane = t & 63;
  const int half = lane >> 5;
  const int site = lane & 31;
  const int bl0  = (blockIdx.x * 8 + w) * 4;   // 4 bl per wave
  const int bl   = bl0 + (site >> 3);
  const int k    = site & 7;

  // ---- features (registers only; half0: f0..f7, half1: f8 + zero pad)
  const float vr = v[bl * 16 + 2 * k], vi = v[bl * 16 + 2 * k + 1];
  s8v A0[3], A1[3], Bf[3];
  {
    float fv[8];
    if (half == 0) {
      float tot = 0.0f, hp = 0.0f;
      #pragma unroll
      for (int kk = 0; kk < 8; kk++) {
        const float hv = ws[WS_HPOW + bl * 8 + kk];
        tot += hv;
        if (kk == k) hp = hv;
      }
      fv[0] = vr;
      fv[1] = vi;
      fv[2] = snr[bl * 8 + k];
      fv[3] = hp;
      fv[4] = ws[WS_AVG + (bl >> 10) * 8 + k];
      fv[5] = log1pf(hp / (tot - hp + 1e-10f));
      fv[6] = log1pf(tot);
      fv[7] = log1pf(ws[WS_YSUM + bl]);
    } else {
      fv[0] = sqrtf(vr * vr + vi * vi + 1e-10f);
      #pragma unroll
      for (int e = 1; e < 8; e++) fv[e] = 0.0f;
    }
    build_frags3(fv, Bf);
  }

  // ---- layer 1 (K=16), with depth-1 A-frag prefetch
  frag_ld(sFr, 0, lane, A0);
  frag_ld(sFr, 1, lane, A1);
  f32x16 c0 = cinit(sB1v, 0, half), c1 = cinit(sB1v, 1, half);
  c0 = mac8(A0, Bf, c0); frag_ld(sFr, 2, lane, A0);
  c1 = mac8(A1, Bf, c1); frag_ld(sFr, 3, lane, A1);
  c0 = relu16(c0); c1 = relu16(c1);

  // ---- layer 2 (K=64, 4 ksteps); A-frags for kstep T+1 load under kstep T
  {
    f32x16 n0 = cinit(sB2v, 0, half), n1 = cinit(sB2v, 1, half);
    bfragC3<0>(c0, c1, half, Bf);
    n0 = mac8(A0, Bf, n0); frag_ld(sFr, 4, lane, A0);
    n1 = mac8(A1, Bf, n1); frag_ld(sFr, 5, lane, A1);
    bfragC3<1>(c0, c1, half, Bf);
    n0 = mac8(A0, Bf, n0); frag_ld(sFr, 6, lane, A0);
    n1 = mac8(A1, Bf, n1); frag_ld(sFr, 7, lane, A1);
    bfragC3<2>(c0, c1, half, Bf);
    n0 = mac8(A0, Bf, n0); frag_ld(sFr, 8, lane, A0);
    n1 = mac8(A1, Bf, n1); frag_ld(sFr, 9, lane, A1);
    bfragC3<3>(c0, c1, half, Bf);
    n0 = mac8(A0, Bf, n0); frag_ld(sFr, 10, lane, A0);
    n1 = mac8(A1, Bf, n1); frag_ld(sFr, 11, lane, A1);
    c0 = relu16(n0); c1 = relu16(n1);
  }
  // ---- layer 3 (calls 10..17; 18,19 prefetched at tail for heads)
  {
    f32x16 n0 = cinit(sB3v, 0, half), n1 = cinit(sB3v, 1, half);
    bfragC3<0>(c0, c1, half, Bf);
    n0 = mac8(A0, Bf, n0); frag_ld(sFr, 12, lane, A0);
    n1 = mac8(A1, Bf, n1); frag_ld(sFr, 13, lane, A1);
    bfragC3<1>(c0, c1, half, Bf);
    n0 = mac8(A0, Bf, n0); frag_ld(sFr, 14, lane, A0);
    n1 = mac8(A1, Bf, n1); frag_ld(sFr, 15, lane, A1);
    bfragC3<2>(c0, c1, half, Bf);
    n0 = mac8(A0, Bf, n0); frag_ld(sFr, 16, lane, A0);
    n1 = mac8(A1, Bf, n1); frag_ld(sFr, 17, lane, A1);
    bfragC3<3>(c0, c1, half, Bf);
    n0 = mac8(A0, Bf, n0); frag_ld(sFr, 18, lane, A0);
    n1 = mac8(A1, Bf, n1); frag_ld(sFr, 19, lane, A1);
    c0 = relu16(n0); c1 = relu16(n1);
  }
  // ---- heads (M-tile 0 only; rows 15..31 zero); calls 18..21, A0/A1 alt
  f32x16 hc = cinit(sBHv, 0, half);
  {
    bfragC3<0>(c0, c1, half, Bf);
    hc = mac8(A0, Bf, hc); frag_ld(sFr, 20, lane, A0);
    bfragC3<1>(c0, c1, half, Bf);
    hc = mac8(A1, Bf, hc); frag_ld(sFr, 21, lane, A1);
    bfragC3<2>(c0, c1, half, Bf);
    hc = mac8(A0, Bf, hc);
    bfragC3<3>(c0, c1, half, Bf);
    hc = mac8(A1, Bf, hc);
  }

  // ---- gather all 16 logits of this lane's site into registers (R10 path)
  float ho[16];
  {
    float hop[8];
    #pragma unroll
    for (int r = 0; r < 8; r++) hop[r] = __shfl_xor(hc[r], 32, 64);
    if (half == 0) {
      #pragma unroll
      for (int r = 0; r < 8; r++) {
        ho[8 * (r >> 2) + (r & 3)]     = hc[r];
        ho[8 * (r >> 2) + 4 + (r & 3)] = hop[r];
      }
    } else {
      #pragma unroll
      for (int r = 0; r < 8; r++) {
        ho[8 * (r >> 2) + 4 + (r & 3)] = hc[r];
        ho[8 * (r >> 2) + (r & 3)]     = hop[r];
      }
    }
  }

  // ---- decisions (all lanes redundant; exact R5 math)
  int bjH, bjD, bjY;
  {
    const float* gg = gH + (bl0 * 8 + site) * 5;
    float bv = ho[5] + gg[0]; int bj = 0;
    #pragma unroll
    for (int c = 1; c < 5; c++) {
      const float lv = ho[5 + c] + gg[c];
      if (lv > bv) { bv = lv; bj = c; }
    }
    bjH = bj;
  }
  {
    const float* gg = gd + (bl0 * 8 + site) * 5;
    float bv = ho[10] + gg[0]; int bj = 0;
    #pragma unroll
    for (int c = 1; c < 5; c++) {
      const float lv = ho[10 + c] + gg[c];
      if (lv > bv) { bv = lv; bj = c; }
    }
    bjD = bj;
  }
  {
    const int gb = lane & 24;
    const float* gg = gy + bl * 5;
    float bv = 0.0f; int bj = 0;
    #pragma unroll
    for (int c = 0; c < 5; c++) {
      float acc = 0.0f;
      #pragma unroll
      for (int kk = 0; kk < 8; kk++) acc += __shfl(ho[c], gb + kk, 64);
      const float lv = acc * 0.125f + gg[c];
      if (c == 0 || lv > bv) { bv = lv; bj = c; }
    }
    bjY = bj;
  }

  // ---- pack H j-codes (3b x 8) + y j-code (3b at bit 27) per bl
  unsigned cH = 0;
  #pragma unroll
  for (int kk = 0; kk < 8; kk++)
    cH |= ((unsigned)__shfl(bjH, (lane & 24) + kk, 64)) << (3 * kk);
  cH |= ((unsigned)bjY) << 27;

  if (lane < 32) {
    if ((site & 7) == 0)
      ((unsigned*)ws)[WS_CODE + bl] = cH;
    {   // b-links
      const int oi = bl0 * 8 + site;
      const float by_ = 64.0f  * (float)bjY;
      const float bH_ = 512.0f * (float)bjH;
      const float bd_ = 8.0f   * (float)bjD;
      out[OFF_BT + oi] = by_ + bH_ + bd_;
      out[OFF_BY + oi] = by_;
      out[OFF_BH + oi] = bH_;
      out[OFF_BD + oi] = bd_;
    }
    {   // v_q (exact-div path retained)
      float dse, dqn, dqp;
      qparamsE<18>(bjD, sd, dse, dqn, dqp);
      float2 r;
      r.x = quantv(vr, dse, dqn, dqp);
      r.y = quantv(vi, dse, dqn, dqp);
      *(float2*)(out + OFF_V + bl0 * 16 + site * 2) = r;
    }
  }
}

// ---------------------------------------------------------------- kernel D
// streaming quant: 2 bl per wave, ALL loads issued before any compute
// (10 float4 in flight per wave); plain stores (fill kernel shows plain
// stores reach 6.9 TB/s -- nt dropped)
__global__ __launch_bounds__(256) void k_hq(const float* __restrict__ Hm,
                                            const float* __restrict__ ym,
                                            const float* __restrict__ sy,
                                            const float* __restrict__ sH,
                                            const float* __restrict__ ws,
                                            float* __restrict__ out) {
  const int t    = threadIdx.x;
  const int lane = t & 63;
  const int bl0  = blockIdx.x * 8 + (t >> 6) * 2;
  const int bl1  = bl0 + 1;

  const unsigned* cws = (const unsigned*)ws;
  const unsigned code0 = cws[WS_CODE + bl0];
  const unsigned code1 = cws[WS_CODE + bl1];

  // ---- issue all loads up front (independent registers -> 10 in flight)
  const float* src0 = Hm + bl0 * 1024;
  const float* src1 = Hm + bl1 * 1024;
  float4 h0[4], h1[4];
  #pragma unroll
  for (int c = 0; c < 4; c++)
    h0[c] = *(const float4*)(src0 + (c * 64 + lane) * 4);
  #pragma unroll
  for (int c = 0; c < 4; c++)
    h1[c] = *(const float4*)(src1 + (c * 64 + lane) * 4);
  float4 yv0 = make_float4(0.f, 0.f, 0.f, 0.f), yv1 = yv0;
  if (lane < 32) {
    yv0 = *(const float4*)(ym + bl0 * 128 + lane * 4);
    yv1 = *(const float4*)(ym + bl1 * 128 + lane * 4);
  }

  // ---- qparams (overlaps the in-flight loads)
  const int k0 = (2 * lane) & 7;
  const int jA0 = (code0 >> (3 * k0)) & 7, jB0 = (code0 >> (3 * (k0 + 1))) & 7;
  const int jY0 = (code0 >> 27) & 7;
  const int jA1 = (code1 >> (3 * k0)) & 7, jB1 = (code1 >> (3 * (k0 + 1))) & 7;
  const int jY1 = (code1 >> 27) & 7;

  float a0se, a0n, a0p, b0se, b0n, b0p, y0se, y0n, y0p;
  float a1se, a1n, a1p, b1se, b1n, b1p, y1se, y1n, y1p;
  qparamsE<24>(jA0, sH, a0se, a0n, a0p);
  qparamsE<24>(jB0, sH, b0se, b0n, b0p);
  qparamsE<21>(jY0, sy, y0se, y0n, y0p);
  qparamsE<24>(jA1, sH, a1se, a1n, a1p);
  qparamsE<24>(jB1, sH, b1se, b1n, b1p);
  qparamsE<21>(jY1, sy, y1se, y1n, y1p);
  const float a0r = 1.0f / a0se, b0r = 1.0f / b0se, y0r = 1.0f / y0se;
  const float a1r = 1.0f / a1se, b1r = 1.0f / b1se, y1r = 1.0f / y1se;

  // ---- quant + store (plain float4 stores)
  float* dst0 = out + OFF_H + bl0 * 1024;
  float* dst1 = out + OFF_H + bl1 * 1024;
  #pragma unroll
  for (int c = 0; c < 4; c++) {
    const int fi = (c * 64 + lane) * 4;
    float4 r;
    r.x = quantr(h0[c].x, a0r, a0se, a0n, a0p);
    r.y = quantr(h0[c].y, a0r, a0se, a0n, a0p);
    r.z = quantr(h0[c].z, b0r, b0se, b0n, b0p);
    r.w = quantr(h0[c].w, b0r, b0se, b0n, b0p);
    *(float4*)(dst0 + fi) = r;
  }
  #pragma unroll
  for (int c = 0; c < 4; c++) {
    const int fi = (c * 64 + lane) * 4;
    float4 r;
    r.x = quantr(h1[c].x, a1r, a1se, a1n, a1p);
    r.y = quantr(h1[c].y, a1r, a1se, a1n, a1p);
    r.z = quantr(h1[c].z, b1r, b1se, b1n, b1p);
    r.w = quantr(h1[c].w, b1r, b1se, b1n, b1p);
    *(float4*)(dst1 + fi) = r;
  }
  if (lane < 32) {
    float4 r;
    r.x = quantr(yv0.x, y0r, y0se, y0n, y0p);
    r.y = quantr(yv0.y, y0r, y0se, y0n, y0p);
    r.z = quantr(yv0.z, y0r, y0se, y0n, y0p);
    r.w = quantr(yv0.w, y0r, y0se, y0n, y0p);
    *(float4*)(out + OFF_Y + bl0 * 128 + lane * 4) = r;
    r.x = quantr(yv1.x, y1r, y1se, y1n, y1p);
    r.y = quantr(yv1.y, y1r, y1se, y1n, y1p);
    r.z = quantr(yv1.z, y1r, y1se, y1n, y1p);
    r.w = quantr(yv1.w, y1r, y1se, y1n, y1p);
    *(float4*)(out + OFF_Y + bl1 * 128 + lane * 4) = r;
  }
}

// ---------------------------------------------------------------- launch
extern "C" void kernel_launch(void* const* d_in, const int* in_sizes, int n_in,
                              void* d_out, int out_size, void* d_ws, size_t ws_size,
                              hipStream_t stream) {
  (void)in_sizes; (void)n_in; (void)out_size; (void)ws_size;
  const float* v   = (const float*)d_in[0];
  const float* Hm  = (const float*)d_in[1];
  const float* ym  = (const float*)d_in[2];
  const float* snr = (const float*)d_in[3];
  const float* gy  = (const float*)d_in[4];
  const float* gH  = (const float*)d_in[5];
  const float* gd  = (const float*)d_in[6];
  const float* W1  = (const float*)d_in[7];
  const float* B1  = (const float*)d_in[8];
  const float* W2  = (const float*)d_in[9];
  const float* B2  = (const float*)d_in[10];
  const float* W3  = (const float*)d_in[11];
  const float* B3  = (const float*)d_in[12];
  const float* Wy  = (const float*)d_in[13];
  const float* By  = (const float*)d_in[14];
  const float* Wh  = (const float*)d_in[15];
  const float* Bh  = (const float*)d_in[16];
  const float* Wd  = (const float*)d_in[17];
  const float* Bd  = (const float*)d_in[18];
  const float* sy  = (const float*)d_in[19];
  const float* sH  = (const float*)d_in[20];
  const float* sd  = (const float*)d_in[21];
  float* out = (float*)d_out;
  float* ws  = (float*)d_ws;

  k_power<<<NBL + 66, 256, 0, stream>>>(Hm, ym, W1, W2, W3, Wy, Wh, Wd, ws);
  k_avg<<<128, 256, 0, stream>>>(ws);
  k_mlp<<<512, 512, 0, stream>>>(v, snr, gy, gH, gd,
                                 B1, B2, B3, By, Bh, Bd, sd, ws, out);
  k_hq<<<2048, 256, 0, stream>>>(Hm, ym, sy, sH, ws, out);
}